// Round 1
// baseline (52.793 us; speedup 1.0000x reference)
//
#include <hip/hip_runtime.h>

#define HW      (768*768)
#define MAXI    33
#define B_IMG   8
#define NBLK    256
#define NTHR    256

// ---------------- Pass 1: per-image histogram of valid pixels ----------------
__global__ __launch_bounds__(NTHR) void pass1_hist(
    const int* __restrict__ inst, const int* __restrict__ ign,
    int* __restrict__ counts)
{
    const int b = blockIdx.y;
    __shared__ int hist[MAXI];
    for (int i = threadIdx.x; i < MAXI; i += NTHR) hist[i] = 0;
    __syncthreads();

    const size_t off = (size_t)b * HW;
    const int4* ip = (const int4*)(inst + off);
    const int4* gp = (const int4*)(ign  + off);
    const int n4 = HW / 4;
    for (int i = blockIdx.x * NTHR + threadIdx.x; i < n4; i += gridDim.x * NTHR) {
        int4 id4 = ip[i];
        int4 g4  = gp[i];
        if (g4.x == 0) atomicAdd(&hist[id4.x], 1);
        if (g4.y == 0) atomicAdd(&hist[id4.y], 1);
        if (g4.z == 0) atomicAdd(&hist[id4.z], 1);
        if (g4.w == 0) atomicAdd(&hist[id4.w], 1);
    }
    __syncthreads();
    for (int i = threadIdx.x; i < MAXI; i += NTHR)
        if (hist[i]) atomicAdd(&counts[b * MAXI + i], hist[i]);
}

// ---------------- Pass 2: weighted L1 partial sums ----------------
__global__ __launch_bounds__(NTHR) void pass2_loss(
    const float* __restrict__ pred, const int* __restrict__ inst,
    const float* __restrict__ gtR,  const float* __restrict__ gts,
    const float* __restrict__ gtc,  const float* __restrict__ gci,
    const int* __restrict__ ign,    const int* __restrict__ counts,
    float* __restrict__ partials)
{
    const int b = blockIdx.y;
    __shared__ float s_w[MAXI];     // per-id weight: id>0 -> 1/(size*n_inst), id==0 -> 1/size
    __shared__ float s_ninv;
    __shared__ float s_red[3][NTHR / 64];

    if (threadIdx.x == 64) {
        int n = 0;
        #pragma unroll
        for (int k = 1; k < MAXI; k++) n += (counts[b * MAXI + k] > 0) ? 1 : 0;
        s_ninv = 1.0f / fmaxf((float)n, 1.0f);
    }
    __syncthreads();
    if (threadIdx.x < MAXI) {
        float sz = fmaxf((float)counts[b * MAXI + threadIdx.x], 1.0f);
        float w = 1.0f / sz;
        if (threadIdx.x > 0) w *= s_ninv;
        s_w[threadIdx.x] = w;
    }
    __syncthreads();

    const size_t off = (size_t)b * HW;
    const float4* p0  = (const float4*)(pred + ((size_t)b * 3 + 0) * HW);
    const float4* p1  = (const float4*)(pred + ((size_t)b * 3 + 1) * HW);
    const float4* p2  = (const float4*)(pred + ((size_t)b * 3 + 2) * HW);
    const int4*   ip  = (const int4*)(inst + off);
    const int4*   gp  = (const int4*)(ign  + off);
    const float4* Rp  = (const float4*)(gtR + off);
    const float4* sp  = (const float4*)(gts + off);
    const float4* cp  = (const float4*)(gtc + off);
    const float4* cip = (const float4*)(gci + off);

    float as = 0.f, ac = 0.f, ar = 0.f;
    const int n4 = HW / 4;
    for (int i = blockIdx.x * NTHR + threadIdx.x; i < n4; i += gridDim.x * NTHR) {
        int4   id4 = ip[i];
        int4   g4  = gp[i];
        float4 R   = Rp[i];
        float4 si  = sp[i];
        float4 co  = cp[i];
        float4 ci  = cip[i];
        float4 a   = p0[i];
        float4 bb  = p1[i];
        float4 cc  = p2[i];

        {
            float w = (g4.x == 0) ? s_w[id4.x] * ci.x : 0.f;
            as += w * fabsf(a.x - si.x);
            ac += w * fabsf(bb.x - co.x);
            ar += w * fabsf(cc.x - __logf(R.x + 1.f));
        }
        {
            float w = (g4.y == 0) ? s_w[id4.y] * ci.y : 0.f;
            as += w * fabsf(a.y - si.y);
            ac += w * fabsf(bb.y - co.y);
            ar += w * fabsf(cc.y - __logf(R.y + 1.f));
        }
        {
            float w = (g4.z == 0) ? s_w[id4.z] * ci.z : 0.f;
            as += w * fabsf(a.z - si.z);
            ac += w * fabsf(bb.z - co.z);
            ar += w * fabsf(cc.z - __logf(R.z + 1.f));
        }
        {
            float w = (g4.w == 0) ? s_w[id4.w] * ci.w : 0.f;
            as += w * fabsf(a.w - si.w);
            ac += w * fabsf(bb.w - co.w);
            ar += w * fabsf(cc.w - __logf(R.w + 1.f));
        }
    }

    // wave64 reduce
    #pragma unroll
    for (int o = 32; o > 0; o >>= 1) {
        as += __shfl_down(as, o);
        ac += __shfl_down(ac, o);
        ar += __shfl_down(ar, o);
    }
    const int wave = threadIdx.x >> 6;
    const int lane = threadIdx.x & 63;
    if (lane == 0) { s_red[0][wave] = as; s_red[1][wave] = ac; s_red[2][wave] = ar; }
    __syncthreads();
    if (threadIdx.x == 0) {
        float ts = 0.f, tc = 0.f, tr = 0.f;
        #pragma unroll
        for (int wv = 0; wv < NTHR / 64; wv++) {
            ts += s_red[0][wv]; tc += s_red[1][wv]; tr += s_red[2][wv];
        }
        float* pp = partials + ((size_t)b * gridDim.x + blockIdx.x) * 3;
        pp[0] = ts; pp[1] = tc; pp[2] = tr;
    }
}

// ---------------- Pass 3: deterministic final reduce + output write ----------------
__global__ __launch_bounds__(NTHR) void pass3_reduce(
    const float* __restrict__ partials, float* __restrict__ out, int nblk)
{
    const int b = blockIdx.x;
    float s = 0.f, c = 0.f, r = 0.f;
    for (int i = threadIdx.x; i < nblk; i += NTHR) {
        const float* pp = partials + ((size_t)b * nblk + i) * 3;
        s += pp[0]; c += pp[1]; r += pp[2];
    }
    #pragma unroll
    for (int o = 32; o > 0; o >>= 1) {
        s += __shfl_down(s, o);
        c += __shfl_down(c, o);
        r += __shfl_down(r, o);
    }
    __shared__ float sr[3][NTHR / 64];
    const int wave = threadIdx.x >> 6;
    const int lane = threadIdx.x & 63;
    if (lane == 0) { sr[0][wave] = s; sr[1][wave] = c; sr[2][wave] = r; }
    __syncthreads();
    if (threadIdx.x == 0) {
        float ts = 0.f, tc = 0.f, tr = 0.f;
        #pragma unroll
        for (int wv = 0; wv < NTHR / 64; wv++) {
            ts += sr[0][wv]; tc += sr[1][wv]; tr += sr[2][wv];
        }
        float tot = ts + tc + tr;
        out[     b] = tot;
        out[ 8 + b] = 0.f;
        out[16 + b] = tot;
        out[24 + b] = 0.f;
        out[32 + b] = ts;
        out[40 + b] = tc;
        out[48 + b] = tr;
        out[56 + b] = 0.f;
    }
}

extern "C" void kernel_launch(void* const* d_in, const int* in_sizes, int n_in,
                              void* d_out, int out_size, void* d_ws, size_t ws_size,
                              hipStream_t stream) {
    const float* pred = (const float*)d_in[0];
    const int*   inst = (const int*)d_in[1];
    // d_in[2] = label (unused by the reference)
    const float* gtR  = (const float*)d_in[3];
    const float* gts  = (const float*)d_in[4];
    const float* gtc  = (const float*)d_in[5];
    const float* gci  = (const float*)d_in[6];
    const int*   ign  = (const int*)d_in[7];
    float* out = (float*)d_out;

    int*   counts   = (int*)d_ws;
    float* partials = (float*)((char*)d_ws + 4096);

    hipMemsetAsync(counts, 0, B_IMG * MAXI * sizeof(int), stream);

    dim3 grid(NBLK, B_IMG);
    pass1_hist<<<grid, NTHR, 0, stream>>>(inst, ign, counts);
    pass2_loss<<<grid, NTHR, 0, stream>>>(pred, inst, gtR, gts, gtc, gci, ign, counts, partials);
    pass3_reduce<<<B_IMG, NTHR, 0, stream>>>(partials, out, NBLK);
}